// Round 5
// baseline (274.752 us; speedup 1.0000x reference)
//
#include <hip/hip_runtime.h>
#include <cstdint>
#include <cstddef>

constexpr int kN   = 50000;          // nodes
constexpr int kE   = 800000;         // edges (without self loops)
constexpr int kEt  = kE + kN;        // edges + self loops
constexpr float kSlope = 0.2f;       // leaky relu slope
constexpr int kScanB = (kN + 255) / 256;       // 196 scan blocks
constexpr int kConvB = (kN * 16 + 255) / 256;  // x-conversion blocks (3125)
constexpr int kHistB = (kEt + 255) / 256;      // per-edge grid (3321)
constexpr int kQuarB = (kN * 16 + 255) / 256;  // quarter-per-node kernels (3125)
// LDS counting-sort geometry: 256 blocks -> all CUs active (was 64 -> 1/4 idle)
constexpr int kHBlk  = 256;                        // histogram blocks
constexpr int kChunk = (kEt + kHBlk - 1) / kHBlk;  // 3321 edges/block (<2^16)
constexpr int kHalfN = kN / 2;                     // 25000 packed u16 pairs

typedef __attribute__((ext_vector_type(8))) short bf8_t;   // 8 bf16 = 4 VGPRs
typedef __attribute__((ext_vector_type(4))) float f4_t;
typedef __attribute__((ext_vector_type(2))) float f2_t;    // packs to v_pk_* on gfx950

// ---------------- static device workspace (d_ws unused) ---------------------
__device__ __align__(16) unsigned short g_xb[(size_t)kN * 128];     // x in bf16
__device__ __align__(16) unsigned short g_aggx[(size_t)kN * 512];   // agg of x, bf16
__device__ __align__(16) unsigned short g_w1t[4 * 128 * 128];       // W1^T per head, bf16
__device__ __align__(16) float g_u[3][512];     // W2 @ [a2s, a2d, fcw]
__device__ __align__(16) float g_es1[kN * 4];
__device__ __align__(16) float g_ed1[kN * 4];
__device__ __align__(16) float2 g_sp[kN];       // {es2, phi} packed
__device__ float g_ed2[kN];
__device__ float g_c0;                          // b2 . fcw + fcb
__device__ __align__(16) float g_p1s[4 * 128];  // folded W1_h @ a1_src_h
__device__ __align__(16) float g_p1d[4 * 128];
// CSR by destination (atomic-free build):
__device__ int g_deg[kN];                       // written by k_pass2 each call
__device__ int g_ptr[kN + 1];
__device__ int g_rank[kEt];                     // rank within (chunk, dst)
__device__ __align__(16) unsigned g_bhist[(size_t)kHBlk * kHalfN];  // per-chunk hist
__device__ __align__(16) unsigned g_bbase[(size_t)kHBlk * kHalfN];  // cross-chunk prefix
__device__ int g_srcs[kEt];
__device__ int g_bsum[kScanB];

__device__ __forceinline__ float lrelu(float x) { return x > 0.f ? x : kSlope * x; }

__device__ __forceinline__ bf8_t bf8_zero() {
  uint4 z = make_uint4(0u, 0u, 0u, 0u);
  return *(bf8_t*)&z;
}

// round-to-nearest-even f32 -> bf16
__device__ __forceinline__ unsigned short f2bf1(float v) {
  unsigned u = __float_as_uint(v);
  unsigned r = (u + 0x7FFFu + ((u >> 16) & 1u)) >> 16;
  return (unsigned short)r;
}

// ---- LDS counting-sort pass 1: per-chunk histogram + in-chunk ranks --------
// 50000 dsts as 25000 packed u16 counters = 100 KB LDS (gfx950 has 160 KB/CU).
// Per-chunk counts < kChunk < 2^16, so packed fields never carry.
__global__ __launch_bounds__(256) void k_hist(const int* __restrict__ ei) {
  __shared__ unsigned sh[kHalfN];
  const int b = blockIdx.x, t = threadIdx.x;
  for (int i = t; i < kHalfN; i += 256) sh[i] = 0u;
  __syncthreads();
  const int beg = b * kChunk, end = min(beg + kChunk, kEt);
  for (int e = beg + t; e < end; e += 256) {
    int d = (e < kE) ? ei[kE + e] : e - kE;
    unsigned inc = (d & 1) ? 0x10000u : 1u;
    unsigned old = atomicAdd(&sh[d >> 1], inc);
    g_rank[e] = (d & 1) ? (int)(old >> 16) : (int)(old & 0xFFFFu);
  }
  __syncthreads();
  unsigned* dst = g_bhist + (size_t)b * kHalfN;
  for (int i = t; i < kHalfN; i += 256) dst[i] = sh[i];
}

// ---- pass 2: per-dst prefix across chunks; emits g_bbase and g_deg ---------
// Iteration b reads a contiguous 100 KB slab across the thread block -> streams.
__global__ __launch_bounds__(256) void k_pass2() {
  const int i = blockIdx.x * 256 + threadIdx.x;
  if (i >= kHalfN) return;
  unsigned c0 = 0, c1 = 0;
#pragma unroll 4
  for (int b = 0; b < kHBlk; ++b) {
    unsigned v = g_bhist[(size_t)b * kHalfN + i];
    g_bbase[(size_t)b * kHalfN + i] = c0 | (c1 << 16);
    c0 += v & 0xFFFFu;
    c1 += v >> 16;
  }
  *(int2*)&g_deg[2 * i] = make_int2((int)c0, (int)c1);
}

// -- merged init: zero(sp,ed2) | W1 conv | prep1 | U | c0 | x->bf16 ----------
__global__ __launch_bounds__(256) void k_init(const float* __restrict__ x,
    const float* __restrict__ W1, const float* __restrict__ W2,
    const float* __restrict__ a1s, const float* __restrict__ a1d,
    const float* __restrict__ a2s, const float* __restrict__ a2d,
    const float* __restrict__ b2, const float* __restrict__ fcw,
    const float* __restrict__ fcb) {
  const int b = blockIdx.x, t = threadIdx.x;
  if (b < 197) {
    int i = b * 256 + t;
    if (i < kN) {
      g_sp[i] = make_float2(0.f, 0.f);
      g_ed2[i] = 0.f;
    }
  } else if (b < 453) {
    int gid = (b - 197) * 256 + t;   // 0..65535 : W1 -> per-head W1^T bf16
    int h = gid >> 14, rem = gid & 16383;
    int c = rem >> 7, j = rem & 127;
    float v = W1[(size_t)c * 512 + h * 128 + j];
    g_w1t[((size_t)h * 128 + j) * 128 + c] = f2bf1(v);
  } else if (b < 457) {
    int gid = (b - 453) * 256 + t;   // 0..1023 : fold a1 through W1
    int which = gid >> 9, idx = gid & 511;
    int h = idx >> 7, k = idx & 127;
    const float* a = which ? a1d : a1s;
    const float* wrow = W1 + (size_t)k * 512 + h * 128;
    float s = 0.f;
#pragma unroll 8
    for (int c = 0; c < 128; ++c) s += wrow[c] * a[h * 128 + c];
    (which ? g_p1d : g_p1s)[idx] = s;
  } else if (b < 463) {
    int gid = (b - 457) * 256 + t;   // 0..1535 : U[v][k] = W2[k,:] . V_v
    if (gid < 1536) {
      int v = gid >> 9, k = gid & 511;
      const float* vv = v == 0 ? a2s : v == 1 ? a2d : fcw;
      const float* wrow = W2 + (size_t)k * 128;
      float s = 0.f;
#pragma unroll 8
      for (int c = 0; c < 128; ++c) s += wrow[c] * vv[c];
      g_u[v][k] = s;
    }
  } else if (b < 464) {
    if (t < 64) {
      float s = b2[t] * fcw[t] + b2[64 + t] * fcw[64 + t];
#pragma unroll
      for (int off = 32; off > 0; off >>= 1) s += __shfl_down(s, off);
      if (t == 0) g_c0 = s + fcb[0];
    }
  } else {
    // x -> bf16, 8 elems per thread
    int g = (b - 464) * 256 + t;
    if (g < kN * 16) {
      const float* xp = x + (size_t)g * 8;
      float4 f0 = *(const float4*)xp;
      float4 f1 = *(const float4*)(xp + 4);
      unsigned w0 = (unsigned)f2bf1(f0.x) | ((unsigned)f2bf1(f0.y) << 16);
      unsigned w1 = (unsigned)f2bf1(f0.z) | ((unsigned)f2bf1(f0.w) << 16);
      unsigned w2 = (unsigned)f2bf1(f1.x) | ((unsigned)f2bf1(f1.y) << 16);
      unsigned w3 = (unsigned)f2bf1(f1.z) | ((unsigned)f2bf1(f1.w) << 16);
      *(uint4*)(g_xb + (size_t)g * 8) = make_uint4(w0, w1, w2, w3);
    }
  }
}

// ---- layer-1 scores (quarter-per-node), folded into k_scanA ----------------
__device__ __forceinline__ void scores1_body(const float* __restrict__ x,
                                             int bid, int t) {
  const int lane = t & 63;
  const int qt = lane >> 4, ql = lane & 15;
  const int n = ((bid * 256 + t) >> 6) * 4 + qt;
  if (n >= kN) return;
  const float* xp = x + (size_t)n * 128 + ql * 8;
  float4 xa = *(const float4*)xp;
  float4 xb = *(const float4*)(xp + 4);
  float s[4], d[4];
#pragma unroll
  for (int h = 0; h < 4; ++h) {
    const float* ps = g_p1s + h * 128 + ql * 8;
    const float* pd = g_p1d + h * 128 + ql * 8;
    s[h] = xa.x * ps[0] + xa.y * ps[1] + xa.z * ps[2] + xa.w * ps[3]
         + xb.x * ps[4] + xb.y * ps[5] + xb.z * ps[6] + xb.w * ps[7];
    d[h] = xa.x * pd[0] + xa.y * pd[1] + xa.z * pd[2] + xa.w * pd[3]
         + xb.x * pd[4] + xb.y * pd[5] + xb.z * pd[6] + xb.w * pd[7];
  }
#pragma unroll
  for (int off = 1; off < 16; off <<= 1) {
#pragma unroll
    for (int h = 0; h < 4; ++h) {
      s[h] += __shfl_xor(s[h], off);
      d[h] += __shfl_xor(d[h], off);
    }
  }
  if (ql == 0) {
    *(float4*)(g_es1 + (size_t)n * 4) = make_float4(s[0], s[1], s[2], s[3]);
    *(float4*)(g_ed1 + (size_t)n * 4) = make_float4(d[0], d[1], d[2], d[3]);
  }
}

// ---- parallel scan, phase A: per-256-chunk LDS scan + block sums -----------
// Blocks >= kScanB run the (independent) layer-1 score computation.
__global__ __launch_bounds__(256) void k_scanA(const float* __restrict__ x) {
  __shared__ int s[256];
  const int b = blockIdx.x, t = threadIdx.x;
  if (b >= kScanB) {
    scores1_body(x, b - kScanB, t);
    return;
  }
  const int i = b * 256 + t;
  int d = (i < kN) ? g_deg[i] : 0;
  s[t] = d;
  __syncthreads();
  for (int off = 1; off < 256; off <<= 1) {
    int v = s[t];
    int u = (t >= off) ? s[t - off] : 0;
    __syncthreads();
    s[t] = v + u;
    __syncthreads();
  }
  if (t == 255) g_bsum[b] = s[255];
  if (i < kN) g_ptr[i] = s[t] - d;   // local exclusive
}

// ---- phase C (merged B): every block scans bsum in LDS, adds its offset ----
__global__ __launch_bounds__(256) void k_scanC() {
  __shared__ int s[256];
  const int b = blockIdx.x, t = threadIdx.x;
  int v = (t < kScanB) ? g_bsum[t] : 0;
  s[t] = v;
  __syncthreads();
  for (int off = 1; off < 256; off <<= 1) {
    int a = s[t];
    int u = (t >= off) ? s[t - off] : 0;
    __syncthreads();
    s[t] = a + u;
    __syncthreads();
  }
  const int boff = (b > 0) ? s[b - 1] : 0;   // exclusive offset for this block
  __syncthreads();
  const int i = b * 256 + t;
  if (i < kN) g_ptr[i] = g_ptr[i] + boff;
  if (b == 0 && t == 0) g_ptr[kN] = kEt;
}

// ---- scatter, atomic-free: slot = ptr[d] + bbase[chunk][d] + rank[e] -------
__global__ __launch_bounds__(256) void k_scatter(const int* __restrict__ ei) {
  int e = blockIdx.x * 256 + threadIdx.x;
  if (e >= kEt) return;
  int s, d;
  if (e < kE) { s = ei[e]; d = ei[kE + e]; } else { s = d = e - kE; }
  const int b = e / kChunk;
  unsigned base = g_bbase[(size_t)b * kHalfN + (d >> 1)];
  base = (d & 1) ? (base >> 16) : (base & 0xFFFFu);
  g_srcs[g_ptr[d] + (int)base + g_rank[e]] = s;
}

// ---- layer-1 aggregation v3: quarter-per-node ------------------------------
// Each 16-lane quarter owns one node: 16 lanes x 16B = full 256B feature row
// per gather. 4 independent nodes per wave -> 4 memory chains in flight,
// full lane use in the weight phase, NO cross-quarter accumulator reduce.
__global__ __launch_bounds__(256) void k_agg1x() {
  const int lane = threadIdx.x & 63;
  const int qt = lane >> 4, ql = lane & 15;
  const int n = ((blockIdx.x * 256 + threadIdx.x) >> 6) * 4 + qt;
  if (n >= kN) return;
  const int beg = g_ptr[n], end = g_ptr[n + 1];
  const float4 ed = *(const float4*)(g_ed1 + (size_t)n * 4);
  const int lbase = qt * 16;
  float z0 = 0.f, z1 = 0.f, z2 = 0.f, z3 = 0.f;
  f2_t acc[4][4] = {};   // [head][feat-pair]; lane owns feats ql*8..ql*8+7
  for (int base = beg; base < end; base += 16) {
    const int cnt = min(16, end - base);
    int s = 0;
    float w0 = 0.f, w1 = 0.f, w2 = 0.f, w3 = 0.f;
    if (ql < cnt) {
      s = g_srcs[base + ql];
      float4 es = *(const float4*)(g_es1 + (size_t)s * 4);
      w0 = __expf(lrelu(es.x + ed.x));
      w1 = __expf(lrelu(es.y + ed.y));
      w2 = __expf(lrelu(es.z + ed.z));
      w3 = __expf(lrelu(es.w + ed.w));
      z0 += w0; z1 += w1; z2 += w2; z3 += w3;
    }
    auto proc = [&](const uint4& uu, int e) {
      float b0 = __shfl(w0, lbase + e), b1 = __shfl(w1, lbase + e);
      float b2 = __shfl(w2, lbase + e), b3 = __shfl(w3, lbase + e);
      f2_t bb0 = b0, bb1 = b1, bb2 = b2, bb3 = b3;
      unsigned ws[4] = {uu.x, uu.y, uu.z, uu.w};
#pragma unroll
      for (int d = 0; d < 4; ++d) {
        f2_t fv;
        fv[0] = __uint_as_float(ws[d] << 16);
        fv[1] = __uint_as_float(ws[d] & 0xFFFF0000u);
        acc[0][d] += bb0 * fv;
        acc[1][d] += bb1 * fv;
        acc[2][d] += bb2 * fv;
        acc[3][d] += bb3 * fv;
      }
    };
    int e = 0;
    // 4-deep gather batching per quarter (x4 quarters = 16 loads in flight)
    for (; e + 4 <= cnt; e += 4) {
      int sj0 = __shfl(s, lbase + e);
      int sj1 = __shfl(s, lbase + e + 1);
      int sj2 = __shfl(s, lbase + e + 2);
      int sj3 = __shfl(s, lbase + e + 3);
      uint4 u0 = *(const uint4*)(g_xb + (size_t)sj0 * 128 + ql * 8);
      uint4 u1 = *(const uint4*)(g_xb + (size_t)sj1 * 128 + ql * 8);
      uint4 u2 = *(const uint4*)(g_xb + (size_t)sj2 * 128 + ql * 8);
      uint4 u3 = *(const uint4*)(g_xb + (size_t)sj3 * 128 + ql * 8);
      proc(u0, e);
      proc(u1, e + 1);
      proc(u2, e + 2);
      proc(u3, e + 3);
    }
    for (; e < cnt; ++e) {
      int sj = __shfl(s, lbase + e);
      uint4 uu = *(const uint4*)(g_xb + (size_t)sj * 128 + ql * 8);
      proc(uu, e);
    }
  }
  // z reduce within the 16-lane quarter
#pragma unroll
  for (int off = 1; off < 16; off <<= 1) {
    z0 += __shfl_xor(z0, off); z1 += __shfl_xor(z1, off);
    z2 += __shfl_xor(z2, off); z3 += __shfl_xor(z3, off);
  }
  const float iz[4] = {1.f / z0, 1.f / z1, 1.f / z2, 1.f / z3};
  const size_t nb = (size_t)n * 512 + ql * 8;
#pragma unroll
  for (int h = 0; h < 4; ++h) {
    unsigned wd[4];
#pragma unroll
    for (int d = 0; d < 4; ++d) {
      f2_t v = acc[h][d] * iz[h];
      wd[d] = (unsigned)f2bf1(v[0]) | ((unsigned)f2bf1(v[1]) << 16);
    }
    *(uint4*)(g_aggx + nb + h * 128) = make_uint4(wd[0], wd[1], wd[2], wd[3]);
  }
}

// ------- fused layer-1 expand + layer-2 projections, head-split -------------
__global__ __launch_bounds__(256) void k_fused(const float* __restrict__ b1) {
  __shared__ float sred[2][64][3];
  const int t = threadIdx.x;
  const int lane = t & 63, w = t >> 6;
  const int wrow = w >> 1, wcol = w & 1;
  const int ln15 = lane & 15, q = lane >> 4, qo = q * 8;
  const int row0 = blockIdx.y * 64;
  const int h = blockIdx.z;

  float part[2][4][3] = {};      // [i][reg][v]
  f4_t h1acc[2][4] = {};
#pragma unroll
  for (int ks = 0; ks < 128; ks += 32) {
    bf8_t ah[2];
#pragma unroll
    for (int i = 0; i < 2; ++i) {
      int r = row0 + wrow * 32 + i * 16 + ln15;
      ah[i] = bf8_zero();
      if (r < kN)
        ah[i] = *(const bf8_t*)&g_aggx[(size_t)r * 512 + h * 128 + ks + qo];
    }
#pragma unroll
    for (int j = 0; j < 4; ++j) {
      size_t gb = ((size_t)h * 128 + wcol * 64 + j * 16 + ln15) * 128 + ks + qo;
      bf8_t bh = *(const bf8_t*)&g_w1t[gb];
#pragma unroll
      for (int i = 0; i < 2; ++i)
        h1acc[i][j] = __builtin_amdgcn_mfma_f32_16x16x32_bf16(ah[i], bh, h1acc[i][j], 0, 0, 0);
    }
  }
  // epilogue: relu(h1+b1) dotted with U columns
#pragma unroll
  for (int j = 0; j < 4; ++j) {
    int col = h * 128 + wcol * 64 + j * 16 + ln15;
    float bv = b1[col];
    float u0 = g_u[0][col], u1 = g_u[1][col], u2 = g_u[2][col];
#pragma unroll
    for (int i = 0; i < 2; ++i)
#pragma unroll
      for (int reg = 0; reg < 4; ++reg) {
        float v = fmaxf(h1acc[i][j][reg] + bv, 0.f);
        part[i][reg][0] += v * u0;
        part[i][reg][1] += v * u1;
        part[i][reg][2] += v * u2;
      }
  }
  // reduce over the 16 lanes of each quad-group (same q)
#pragma unroll
  for (int off = 1; off < 16; off <<= 1)
#pragma unroll
    for (int i = 0; i < 2; ++i)
#pragma unroll
      for (int reg = 0; reg < 4; ++reg)
#pragma unroll
        for (int v = 0; v < 3; ++v)
          part[i][reg][v] += __shfl_xor(part[i][reg][v], off);
  if (ln15 == 0) {
#pragma unroll
    for (int i = 0; i < 2; ++i)
#pragma unroll
      for (int reg = 0; reg < 4; ++reg) {
        int rl = wrow * 32 + i * 16 + q * 4 + reg;
#pragma unroll
        for (int v = 0; v < 3; ++v) sred[wcol][rl][v] = part[i][reg][v];
      }
  }
  __syncthreads();
  if (t < 192) {
    int row = t / 3, v = t - row * 3;
    float s = sred[0][row][v] + sred[1][row][v];
    int r = row0 + row;
    if (r < kN) {
      float* dst = v == 0 ? &g_sp[r].x : v == 1 ? &g_ed2[r] : &g_sp[r].y;
      atomicAdd(dst, s);
    }
  }
}

// ---- layer-2 aggregation v2: quarter-per-node + output ---------------------
__global__ __launch_bounds__(256) void k_agg2s(float* __restrict__ out) {
  const int lane = threadIdx.x & 63;
  const int qt = lane >> 4, ql = lane & 15;
  const int n = ((blockIdx.x * 256 + threadIdx.x) >> 6) * 4 + qt;
  if (n >= kN) return;
  const int beg = g_ptr[n], end = g_ptr[n + 1];
  const float ed = g_ed2[n];
  float zp = 0.f, num = 0.f;
  for (int slot = beg + ql; slot < end; slot += 16) {
    int s = g_srcs[slot];
    float2 sp = g_sp[s];
    float w = __expf(lrelu(sp.x + ed));
    zp += w;
    num += w * sp.y;
  }
#pragma unroll
  for (int off = 1; off < 16; off <<= 1) {
    zp  += __shfl_xor(zp, off);
    num += __shfl_xor(num, off);
  }
  if (ql == 0) out[n] = num / zp + g_c0;
}

extern "C" void kernel_launch(void* const* d_in, const int* in_sizes, int n_in,
                              void* d_out, int out_size, void* d_ws, size_t ws_size,
                              hipStream_t stream) {
  const float* x   = (const float*)d_in[0];
  const int*   ei  = (const int*)d_in[1];
  const float* W1  = (const float*)d_in[2];
  const float* a1s = (const float*)d_in[3];
  const float* a1d = (const float*)d_in[4];
  const float* b1  = (const float*)d_in[5];
  const float* W2  = (const float*)d_in[6];
  const float* a2s = (const float*)d_in[7];
  const float* a2d = (const float*)d_in[8];
  const float* b2  = (const float*)d_in[9];
  const float* fcw = (const float*)d_in[10];
  const float* fcb = (const float*)d_in[11];
  float* out = (float*)d_out;
  (void)d_ws; (void)ws_size; (void)in_sizes; (void)n_in; (void)out_size;

  // ---- CSR counting sort, pass 1 (LDS hist + ranks; 256 blocks) ----
  k_hist<<<kHBlk, 256, 0, stream>>>(ei);
  // ---- init (zero | W1 conv | prep1 | U | c0 | x->bf16) ----
  k_init<<<464 + kConvB, 256, 0, stream>>>(x, W1, W2, a1s, a1d,
                                           a2s, a2d, b2, fcw, fcb);
  // ---- CSR pass 2 + ptr scan (scanA also carries layer-1 scores blocks) ---
  k_pass2<<<(kHalfN + 255) / 256, 256, 0, stream>>>();
  k_scanA<<<kScanB + kQuarB, 256, 0, stream>>>(x);
  k_scanC<<<kScanB, 256, 0, stream>>>();
  k_scatter<<<kHistB, 256, 0, stream>>>(ei);

  // ---- layer 1 aggregation (quarter-per-node) ----
  k_agg1x<<<kQuarB, 256, 0, stream>>>();

  // ---- fused expand + layer-2 projections (head-split, atomic combine) ----
  dim3 gf(1, (kN + 63) / 64, 4);
  k_fused<<<gf, 256, 0, stream>>>(b1);

  // ---- layer-2 edge aggregation (quarter-per-node) + output ----
  k_agg2s<<<kQuarB, 256, 0, stream>>>(out);
}

// Round 7
// 258.549 us; speedup vs baseline: 1.0627x; 1.0627x over previous
//
#include <hip/hip_runtime.h>
#include <cstdint>
#include <cstddef>

constexpr int kN   = 50000;          // nodes
constexpr int kE   = 800000;         // edges (without self loops)
constexpr int kEt  = kE + kN;        // edges + self loops
constexpr float kSlope = 0.2f;       // leaky relu slope
constexpr int kScanB = (kN + 255) / 256;       // 196 scan blocks
constexpr int kConvB = (kN * 16 + 255) / 256;  // x-conversion blocks (3125)
constexpr int kHistB = (kEt + 255) / 256;      // per-edge grid (3321)
constexpr int kQuarB = (kN * 16 + 255) / 256;  // quarter-per-node kernels (3125)
// LDS counting-sort geometry: 64 chunks x 4 dst-ranges = 256 blocks.
// Table traffic stays at the 64-chunk minimum (6.4 MB) while every CU gets a
// block and the per-block LDS table is only 25 KB (fixed zero/dump cost /4).
constexpr int kHChunks = 64;                           // edge chunks
constexpr int kChunk   = (kEt + kHChunks - 1) / kHChunks;  // 13282 (<2^16)
constexpr int kHRanges = 4;                            // dst ranges
constexpr int kRangeN  = kN / kHRanges;                // 12500 dsts/range (even)
constexpr int kRangeH  = kRangeN / 2;                  // 6250 packed u16 pairs
constexpr int kHalfN   = kN / 2;                       // 25000 pairs total

typedef __attribute__((ext_vector_type(8))) short bf8_t;   // 8 bf16 = 4 VGPRs
typedef __attribute__((ext_vector_type(4))) float f4_t;
typedef __attribute__((ext_vector_type(2))) float f2_t;    // packs to v_pk_* on gfx950

// ---------------- static device workspace (d_ws unused) ---------------------
__device__ __align__(16) unsigned short g_xb[(size_t)kN * 128];     // x in bf16
__device__ __align__(16) unsigned short g_aggx[(size_t)kN * 512];   // agg of x, bf16
__device__ __align__(16) unsigned short g_w1t[4 * 128 * 128];       // W1^T per head, bf16
__device__ __align__(16) float g_u[3][512];     // W2 @ [a2s, a2d, fcw]
__device__ __align__(16) float g_es1[kN * 4];
__device__ __align__(16) float g_ed1[kN * 4];
__device__ __align__(16) float2 g_sp[kN];       // {es2, phi} packed
__device__ float g_ed2[kN];
__device__ float g_c0;                          // b2 . fcw + fcb
__device__ __align__(16) float g_p1s[4 * 128];  // folded W1_h @ a1_src_h
__device__ __align__(16) float g_p1d[4 * 128];
// CSR by destination (atomic-free build):
__device__ int g_deg[kN];                       // written by k_pass2 each call
__device__ int g_ptr[kN + 1];
__device__ int g_rank[kEt];                     // rank within (chunk, dst)
__device__ __align__(16) unsigned g_bhist[(size_t)kHChunks * kHalfN];  // per-chunk hist
__device__ __align__(16) unsigned g_bbase[(size_t)kHChunks * kHalfN];  // cross-chunk prefix
__device__ int g_srcs[kEt];
__device__ int g_bsum[kScanB];

__device__ __forceinline__ float lrelu(float x) { return x > 0.f ? x : kSlope * x; }

__device__ __forceinline__ bf8_t bf8_zero() {
  uint4 z = make_uint4(0u, 0u, 0u, 0u);
  return *(bf8_t*)&z;
}

// round-to-nearest-even f32 -> bf16
__device__ __forceinline__ unsigned short f2bf1(float v) {
  unsigned u = __float_as_uint(v);
  unsigned r = (u + 0x7FFFu + ((u >> 16) & 1u)) >> 16;
  return (unsigned short)r;
}

// ---- LDS counting-sort pass 1: (chunk, dst-range) histogram + ranks --------
// Block b = range (b>>6) x chunk (b&63). Each block counts only dsts in its
// 12500-wide range: 25 KB LDS table, 256 blocks -> all CUs busy, table dump
// stays at the 64-chunk minimum. Per-(chunk,dst) counts < kChunk < 2^16.
__global__ __launch_bounds__(256) void k_hist(const int* __restrict__ ei) {
  __shared__ unsigned sh[kRangeH];
  const int b = blockIdx.x, t = threadIdx.x;
  const int chunk = b & (kHChunks - 1);
  const int rr = b >> 6;
  const int lo = rr * kRangeN, hi = lo + kRangeN;
  for (int i = t; i < kRangeH; i += 256) sh[i] = 0u;
  __syncthreads();
  const int beg = chunk * kChunk, end = min(beg + kChunk, kEt);
  for (int e = beg + t; e < end; e += 256) {
    int d = (e < kE) ? ei[kE + e] : e - kE;
    if (d >= lo && d < hi) {
      unsigned inc = (d & 1) ? 0x10000u : 1u;
      unsigned old = atomicAdd(&sh[(d - lo) >> 1], inc);
      g_rank[e] = (d & 1) ? (int)(old >> 16) : (int)(old & 0xFFFFu);
    }
  }
  __syncthreads();
  unsigned* dst = g_bhist + (size_t)chunk * kHalfN + rr * kRangeH;
  for (int i = t; i < kRangeH; i += 256) dst[i] = sh[i];
}

// ---- pass 2: per-dst prefix across chunks; emits g_bbase and g_deg ---------
// Iteration b reads a contiguous slab across the thread block -> streams.
__global__ __launch_bounds__(256) void k_pass2() {
  const int i = blockIdx.x * 256 + threadIdx.x;
  if (i >= kHalfN) return;
  unsigned c0 = 0, c1 = 0;
#pragma unroll 4
  for (int b = 0; b < kHChunks; ++b) {
    unsigned v = g_bhist[(size_t)b * kHalfN + i];
    g_bbase[(size_t)b * kHalfN + i] = c0 | (c1 << 16);
    c0 += v & 0xFFFFu;
    c1 += v >> 16;
  }
  *(int2*)&g_deg[2 * i] = make_int2((int)c0, (int)c1);
}

// -- merged init: zero(sp,ed2) | W1 conv | prep1 | U | c0 | x->bf16 ----------
__global__ __launch_bounds__(256) void k_init(const float* __restrict__ x,
    const float* __restrict__ W1, const float* __restrict__ W2,
    const float* __restrict__ a1s, const float* __restrict__ a1d,
    const float* __restrict__ a2s, const float* __restrict__ a2d,
    const float* __restrict__ b2, const float* __restrict__ fcw,
    const float* __restrict__ fcb) {
  const int b = blockIdx.x, t = threadIdx.x;
  if (b < 197) {
    int i = b * 256 + t;
    if (i < kN) {
      g_sp[i] = make_float2(0.f, 0.f);
      g_ed2[i] = 0.f;
    }
  } else if (b < 453) {
    int gid = (b - 197) * 256 + t;   // 0..65535 : W1 -> per-head W1^T bf16
    int h = gid >> 14, rem = gid & 16383;
    int c = rem >> 7, j = rem & 127;
    float v = W1[(size_t)c * 512 + h * 128 + j];
    g_w1t[((size_t)h * 128 + j) * 128 + c] = f2bf1(v);
  } else if (b < 457) {
    int gid = (b - 453) * 256 + t;   // 0..1023 : fold a1 through W1
    int which = gid >> 9, idx = gid & 511;
    int h = idx >> 7, k = idx & 127;
    const float* a = which ? a1d : a1s;
    const float* wrow = W1 + (size_t)k * 512 + h * 128;
    float s = 0.f;
#pragma unroll 8
    for (int c = 0; c < 128; ++c) s += wrow[c] * a[h * 128 + c];
    (which ? g_p1d : g_p1s)[idx] = s;
  } else if (b < 463) {
    int gid = (b - 457) * 256 + t;   // 0..1535 : U[v][k] = W2[k,:] . V_v
    if (gid < 1536) {
      int v = gid >> 9, k = gid & 511;
      const float* vv = v == 0 ? a2s : v == 1 ? a2d : fcw;
      const float* wrow = W2 + (size_t)k * 128;
      float s = 0.f;
#pragma unroll 8
      for (int c = 0; c < 128; ++c) s += wrow[c] * vv[c];
      g_u[v][k] = s;
    }
  } else if (b < 464) {
    if (t < 64) {
      float s = b2[t] * fcw[t] + b2[64 + t] * fcw[64 + t];
#pragma unroll
      for (int off = 32; off > 0; off >>= 1) s += __shfl_down(s, off);
      if (t == 0) g_c0 = s + fcb[0];
    }
  } else {
    // x -> bf16, 8 elems per thread
    int g = (b - 464) * 256 + t;
    if (g < kN * 16) {
      const float* xp = x + (size_t)g * 8;
      float4 f0 = *(const float4*)xp;
      float4 f1 = *(const float4*)(xp + 4);
      unsigned w0 = (unsigned)f2bf1(f0.x) | ((unsigned)f2bf1(f0.y) << 16);
      unsigned w1 = (unsigned)f2bf1(f0.z) | ((unsigned)f2bf1(f0.w) << 16);
      unsigned w2 = (unsigned)f2bf1(f1.x) | ((unsigned)f2bf1(f1.y) << 16);
      unsigned w3 = (unsigned)f2bf1(f1.z) | ((unsigned)f2bf1(f1.w) << 16);
      *(uint4*)(g_xb + (size_t)g * 8) = make_uint4(w0, w1, w2, w3);
    }
  }
}

// ---- layer-1 scores (quarter-per-node), folded into k_scanA ----------------
__device__ __forceinline__ void scores1_body(const float* __restrict__ x,
                                             int bid, int t) {
  const int lane = t & 63;
  const int qt = lane >> 4, ql = lane & 15;
  const int n = ((bid * 256 + t) >> 6) * 4 + qt;
  if (n >= kN) return;
  const float* xp = x + (size_t)n * 128 + ql * 8;
  float4 xa = *(const float4*)xp;
  float4 xb = *(const float4*)(xp + 4);
  float s[4], d[4];
#pragma unroll
  for (int h = 0; h < 4; ++h) {
    const float* ps = g_p1s + h * 128 + ql * 8;
    const float* pd = g_p1d + h * 128 + ql * 8;
    s[h] = xa.x * ps[0] + xa.y * ps[1] + xa.z * ps[2] + xa.w * ps[3]
         + xb.x * ps[4] + xb.y * ps[5] + xb.z * ps[6] + xb.w * ps[7];
    d[h] = xa.x * pd[0] + xa.y * pd[1] + xa.z * pd[2] + xa.w * pd[3]
         + xb.x * pd[4] + xb.y * pd[5] + xb.z * pd[6] + xb.w * pd[7];
  }
#pragma unroll
  for (int off = 1; off < 16; off <<= 1) {
#pragma unroll
    for (int h = 0; h < 4; ++h) {
      s[h] += __shfl_xor(s[h], off);
      d[h] += __shfl_xor(d[h], off);
    }
  }
  if (ql == 0) {
    *(float4*)(g_es1 + (size_t)n * 4) = make_float4(s[0], s[1], s[2], s[3]);
    *(float4*)(g_ed1 + (size_t)n * 4) = make_float4(d[0], d[1], d[2], d[3]);
  }
}

// ---- parallel scan, phase A: per-256-chunk LDS scan + block sums -----------
// Blocks >= kScanB run the (independent) layer-1 score computation.
__global__ __launch_bounds__(256) void k_scanA(const float* __restrict__ x) {
  __shared__ int s[256];
  const int b = blockIdx.x, t = threadIdx.x;
  if (b >= kScanB) {
    scores1_body(x, b - kScanB, t);
    return;
  }
  const int i = b * 256 + t;
  int d = (i < kN) ? g_deg[i] : 0;
  s[t] = d;
  __syncthreads();
  for (int off = 1; off < 256; off <<= 1) {
    int v = s[t];
    int u = (t >= off) ? s[t - off] : 0;
    __syncthreads();
    s[t] = v + u;
    __syncthreads();
  }
  if (t == 255) g_bsum[b] = s[255];
  if (i < kN) g_ptr[i] = s[t] - d;   // local exclusive
}

// ---- phase C (merged B): every block scans bsum in LDS, adds its offset ----
__global__ __launch_bounds__(256) void k_scanC() {
  __shared__ int s[256];
  const int b = blockIdx.x, t = threadIdx.x;
  int v = (t < kScanB) ? g_bsum[t] : 0;
  s[t] = v;
  __syncthreads();
  for (int off = 1; off < 256; off <<= 1) {
    int a = s[t];
    int u = (t >= off) ? s[t - off] : 0;
    __syncthreads();
    s[t] = a + u;
    __syncthreads();
  }
  const int boff = (b > 0) ? s[b - 1] : 0;   // exclusive offset for this block
  __syncthreads();
  const int i = b * 256 + t;
  if (i < kN) g_ptr[i] = g_ptr[i] + boff;
  if (b == 0 && t == 0) g_ptr[kN] = kEt;
}

// ---- scatter, atomic-free: slot = ptr[d] + bbase[chunk][d] + rank[e] -------
__global__ __launch_bounds__(256) void k_scatter(const int* __restrict__ ei) {
  int e = blockIdx.x * 256 + threadIdx.x;
  if (e >= kEt) return;
  int s, d;
  if (e < kE) { s = ei[e]; d = ei[kE + e]; } else { s = d = e - kE; }
  const int b = e / kChunk;
  unsigned base = g_bbase[(size_t)b * kHalfN + (d >> 1)];
  base = (d & 1) ? (base >> 16) : (base & 0xFFFFu);
  g_srcs[g_ptr[d] + (int)base + g_rank[e]] = s;
}

// ---- layer-1 aggregation v3: quarter-per-node ------------------------------
// Each 16-lane quarter owns one node: 16 lanes x 16B = full 256B feature row
// per gather. 4 independent nodes per wave -> 4 memory chains in flight,
// full lane use in the weight phase, NO cross-quarter accumulator reduce.
__global__ __launch_bounds__(256) void k_agg1x() {
  const int lane = threadIdx.x & 63;
  const int qt = lane >> 4, ql = lane & 15;
  const int n = ((blockIdx.x * 256 + threadIdx.x) >> 6) * 4 + qt;
  if (n >= kN) return;
  const int beg = g_ptr[n], end = g_ptr[n + 1];
  const float4 ed = *(const float4*)(g_ed1 + (size_t)n * 4);
  const int lbase = qt * 16;
  float z0 = 0.f, z1 = 0.f, z2 = 0.f, z3 = 0.f;
  f2_t acc[4][4] = {};   // [head][feat-pair]; lane owns feats ql*8..ql*8+7
  for (int base = beg; base < end; base += 16) {
    const int cnt = min(16, end - base);
    int s = 0;
    float w0 = 0.f, w1 = 0.f, w2 = 0.f, w3 = 0.f;
    if (ql < cnt) {
      s = g_srcs[base + ql];
      float4 es = *(const float4*)(g_es1 + (size_t)s * 4);
      w0 = __expf(lrelu(es.x + ed.x));
      w1 = __expf(lrelu(es.y + ed.y));
      w2 = __expf(lrelu(es.z + ed.z));
      w3 = __expf(lrelu(es.w + ed.w));
      z0 += w0; z1 += w1; z2 += w2; z3 += w3;
    }
    auto proc = [&](const uint4& uu, int e) {
      float b0 = __shfl(w0, lbase + e), b1 = __shfl(w1, lbase + e);
      float b2 = __shfl(w2, lbase + e), b3 = __shfl(w3, lbase + e);
      f2_t bb0 = b0, bb1 = b1, bb2 = b2, bb3 = b3;
      unsigned ws[4] = {uu.x, uu.y, uu.z, uu.w};
#pragma unroll
      for (int d = 0; d < 4; ++d) {
        f2_t fv;
        fv[0] = __uint_as_float(ws[d] << 16);
        fv[1] = __uint_as_float(ws[d] & 0xFFFF0000u);
        acc[0][d] += bb0 * fv;
        acc[1][d] += bb1 * fv;
        acc[2][d] += bb2 * fv;
        acc[3][d] += bb3 * fv;
      }
    };
    int e = 0;
    // 4-deep gather batching per quarter (x4 quarters = 16 loads in flight)
    for (; e + 4 <= cnt; e += 4) {
      int sj0 = __shfl(s, lbase + e);
      int sj1 = __shfl(s, lbase + e + 1);
      int sj2 = __shfl(s, lbase + e + 2);
      int sj3 = __shfl(s, lbase + e + 3);
      uint4 u0 = *(const uint4*)(g_xb + (size_t)sj0 * 128 + ql * 8);
      uint4 u1 = *(const uint4*)(g_xb + (size_t)sj1 * 128 + ql * 8);
      uint4 u2 = *(const uint4*)(g_xb + (size_t)sj2 * 128 + ql * 8);
      uint4 u3 = *(const uint4*)(g_xb + (size_t)sj3 * 128 + ql * 8);
      proc(u0, e);
      proc(u1, e + 1);
      proc(u2, e + 2);
      proc(u3, e + 3);
    }
    for (; e < cnt; ++e) {
      int sj = __shfl(s, lbase + e);
      uint4 uu = *(const uint4*)(g_xb + (size_t)sj * 128 + ql * 8);
      proc(uu, e);
    }
  }
  // z reduce within the 16-lane quarter
#pragma unroll
  for (int off = 1; off < 16; off <<= 1) {
    z0 += __shfl_xor(z0, off); z1 += __shfl_xor(z1, off);
    z2 += __shfl_xor(z2, off); z3 += __shfl_xor(z3, off);
  }
  const float iz[4] = {1.f / z0, 1.f / z1, 1.f / z2, 1.f / z3};
  const size_t nb = (size_t)n * 512 + ql * 8;
#pragma unroll
  for (int h = 0; h < 4; ++h) {
    unsigned wd[4];
#pragma unroll
    for (int d = 0; d < 4; ++d) {
      f2_t v = acc[h][d] * iz[h];
      wd[d] = (unsigned)f2bf1(v[0]) | ((unsigned)f2bf1(v[1]) << 16);
    }
    *(uint4*)(g_aggx + nb + h * 128) = make_uint4(wd[0], wd[1], wd[2], wd[3]);
  }
}

// ------- fused layer-1 expand + layer-2 projections, head-split -------------
__global__ __launch_bounds__(256) void k_fused(const float* __restrict__ b1) {
  __shared__ float sred[2][64][3];
  const int t = threadIdx.x;
  const int lane = t & 63, w = t >> 6;
  const int wrow = w >> 1, wcol = w & 1;
  const int ln15 = lane & 15, q = lane >> 4, qo = q * 8;
  const int row0 = blockIdx.y * 64;
  const int h = blockIdx.z;

  float part[2][4][3] = {};      // [i][reg][v]
  f4_t h1acc[2][4] = {};
#pragma unroll
  for (int ks = 0; ks < 128; ks += 32) {
    bf8_t ah[2];
#pragma unroll
    for (int i = 0; i < 2; ++i) {
      int r = row0 + wrow * 32 + i * 16 + ln15;
      ah[i] = bf8_zero();
      if (r < kN)
        ah[i] = *(const bf8_t*)&g_aggx[(size_t)r * 512 + h * 128 + ks + qo];
    }
#pragma unroll
    for (int j = 0; j < 4; ++j) {
      size_t gb = ((size_t)h * 128 + wcol * 64 + j * 16 + ln15) * 128 + ks + qo;
      bf8_t bh = *(const bf8_t*)&g_w1t[gb];
#pragma unroll
      for (int i = 0; i < 2; ++i)
        h1acc[i][j] = __builtin_amdgcn_mfma_f32_16x16x32_bf16(ah[i], bh, h1acc[i][j], 0, 0, 0);
    }
  }
  // epilogue: relu(h1+b1) dotted with U columns
#pragma unroll
  for (int j = 0; j < 4; ++j) {
    int col = h * 128 + wcol * 64 + j * 16 + ln15;
    float bv = b1[col];
    float u0 = g_u[0][col], u1 = g_u[1][col], u2 = g_u[2][col];
#pragma unroll
    for (int i = 0; i < 2; ++i)
#pragma unroll
      for (int reg = 0; reg < 4; ++reg) {
        float v = fmaxf(h1acc[i][j][reg] + bv, 0.f);
        part[i][reg][0] += v * u0;
        part[i][reg][1] += v * u1;
        part[i][reg][2] += v * u2;
      }
  }
  // reduce over the 16 lanes of each quad-group (same q)
#pragma unroll
  for (int off = 1; off < 16; off <<= 1)
#pragma unroll
    for (int i = 0; i < 2; ++i)
#pragma unroll
      for (int reg = 0; reg < 4; ++reg)
#pragma unroll
        for (int v = 0; v < 3; ++v)
          part[i][reg][v] += __shfl_xor(part[i][reg][v], off);
  if (ln15 == 0) {
#pragma unroll
    for (int i = 0; i < 2; ++i)
#pragma unroll
      for (int reg = 0; reg < 4; ++reg) {
        int rl = wrow * 32 + i * 16 + q * 4 + reg;
#pragma unroll
        for (int v = 0; v < 3; ++v) sred[wcol][rl][v] = part[i][reg][v];
      }
  }
  __syncthreads();
  if (t < 192) {
    int row = t / 3, v = t - row * 3;
    float s = sred[0][row][v] + sred[1][row][v];
    int r = row0 + row;
    if (r < kN) {
      float* dst = v == 0 ? &g_sp[r].x : v == 1 ? &g_ed2[r] : &g_sp[r].y;
      atomicAdd(dst, s);
    }
  }
}

// ---- layer-2 aggregation v2: quarter-per-node + output ---------------------
__global__ __launch_bounds__(256) void k_agg2s(float* __restrict__ out) {
  const int lane = threadIdx.x & 63;
  const int qt = lane >> 4, ql = lane & 15;
  const int n = ((blockIdx.x * 256 + threadIdx.x) >> 6) * 4 + qt;
  if (n >= kN) return;
  const int beg = g_ptr[n], end = g_ptr[n + 1];
  const float ed = g_ed2[n];
  float zp = 0.f, num = 0.f;
  for (int slot = beg + ql; slot < end; slot += 16) {
    int s = g_srcs[slot];
    float2 sp = g_sp[s];
    float w = __expf(lrelu(sp.x + ed));
    zp += w;
    num += w * sp.y;
  }
#pragma unroll
  for (int off = 1; off < 16; off <<= 1) {
    zp  += __shfl_xor(zp, off);
    num += __shfl_xor(num, off);
  }
  if (ql == 0) out[n] = num / zp + g_c0;
}

extern "C" void kernel_launch(void* const* d_in, const int* in_sizes, int n_in,
                              void* d_out, int out_size, void* d_ws, size_t ws_size,
                              hipStream_t stream) {
  const float* x   = (const float*)d_in[0];
  const int*   ei  = (const int*)d_in[1];
  const float* W1  = (const float*)d_in[2];
  const float* a1s = (const float*)d_in[3];
  const float* a1d = (const float*)d_in[4];
  const float* b1  = (const float*)d_in[5];
  const float* W2  = (const float*)d_in[6];
  const float* a2s = (const float*)d_in[7];
  const float* a2d = (const float*)d_in[8];
  const float* b2  = (const float*)d_in[9];
  const float* fcw = (const float*)d_in[10];
  const float* fcb = (const float*)d_in[11];
  float* out = (float*)d_out;
  (void)d_ws; (void)ws_size; (void)in_sizes; (void)n_in; (void)out_size;

  // ---- CSR counting sort, pass 1 (64 chunks x 4 ranges, 25 KB LDS) ----
  k_hist<<<kHChunks * kHRanges, 256, 0, stream>>>(ei);
  // ---- init (zero | W1 conv | prep1 | U | c0 | x->bf16) ----
  k_init<<<464 + kConvB, 256, 0, stream>>>(x, W1, W2, a1s, a1d,
                                           a2s, a2d, b2, fcw, fcb);
  // ---- CSR pass 2 + ptr scan (scanA also carries layer-1 scores blocks) ---
  k_pass2<<<(kHalfN + 255) / 256, 256, 0, stream>>>();
  k_scanA<<<kScanB + kQuarB, 256, 0, stream>>>(x);
  k_scanC<<<kScanB, 256, 0, stream>>>();
  k_scatter<<<kHistB, 256, 0, stream>>>(ei);

  // ---- layer 1 aggregation (quarter-per-node) ----
  k_agg1x<<<kQuarB, 256, 0, stream>>>();

  // ---- fused expand + layer-2 projections (head-split, atomic combine) ----
  dim3 gf(1, (kN + 63) / 64, 4);
  k_fused<<<gf, 256, 0, stream>>>(b1);

  // ---- layer-2 edge aggregation (quarter-per-node) + output ----
  k_agg2s<<<kQuarB, 256, 0, stream>>>(out);
}